// Round 2
// baseline (239.169 us; speedup 1.0000x reference)
//
#include <hip/hip_runtime.h>
#include <hip/hip_bf16.h>

// KAN layer fused as one augmented GEMM:
//   out[n][o] = sum_i silu(x[n][i])*scale_base[o][i]
//            + sum_{i,m} basis_m(x[n][i])*scale_sp[o][i]*coef[o][i][m] + bias[o]
// A_aug (8192 x 5376) f16, W_aug (768 x 5376) f16, k = j*768 + i (j=0: silu, j=1..6: basis)

typedef _Float16 f16;
typedef __attribute__((ext_vector_type(8))) _Float16 f16x8;
typedef __attribute__((ext_vector_type(4))) float f32x4;

#define NTOK 8192
#define DIN 768
#define DOUT 768
#define KAUG 5376   // 7*768
#define BM 128
#define BN 128
#define BK 32
#define KT (KAUG / BK)  // 168

typedef __attribute__((address_space(1))) void gvoid;
typedef __attribute__((address_space(3))) void lvoid;

// ---------------- Kernel 1: x -> [silu | 6 basis] f16, 8 elems/thread ----------------
// Closed-form uniform cubic B-spline: t_g = (g-3)*(2/3)-1, g=0..9.
// B_m(x) = N3(s - m), s = (x+1)*1.5 + 3. With i0=floor(s), u=s-i0, the 4 nonzero
// basis are m = i0-3..i0 with the standard cubic weights.
__global__ __launch_bounds__(256) void build_A(const float* __restrict__ x,
                                               f16* __restrict__ Aa) {
  const int t = blockIdx.x * 256 + threadIdx.x;  // [0, NTOK*96), exact grid
  const int n = t / 96;                          // 96 = DIN/8
  const int i8 = (t - n * 96) * 8;

  const float4* xp = (const float4*)(x + (size_t)n * DIN + i8);
  float4 va = xp[0], vb = xp[1];
  float xv[8] = {va.x, va.y, va.z, va.w, vb.x, vb.y, vb.z, vb.w};

  f16x8 sil;
  f16x8 Bv[6];
#pragma unroll
  for (int e = 0; e < 8; ++e) {
    const float v = xv[e];
    sil[e] = (f16)__fdividef(v, 1.0f + __expf(-v));

    const float s = (v + 1.0f) * 1.5f + 3.0f;
    const float fi = floorf(s);
    const int i0 = (int)fi;
    const float u = s - fi;
    const float um = 1.0f - u;
    const float u2 = u * u, u3 = u2 * u;
    const float w0 = um * um * um * (1.0f / 6.0f);
    const float w1 = (3.0f * u3 - 6.0f * u2 + 4.0f) * (1.0f / 6.0f);
    const float w2 = (-3.0f * u3 + 3.0f * u2 + 3.0f * u + 1.0f) * (1.0f / 6.0f);
    const float w3 = u3 * (1.0f / 6.0f);
#pragma unroll
    for (int m = 0; m < 6; ++m) {
      const int d = m - i0 + 3;  // which of the 4 weights (0..3), else zero
      float w = (d == 0) ? w0 : (d == 1) ? w1 : (d == 2) ? w2 : (d == 3) ? w3 : 0.0f;
      Bv[m][e] = (f16)w;
    }
  }

  const size_t base = (size_t)n * KAUG + i8;
  *(f16x8*)&Aa[base] = sil;
#pragma unroll
  for (int m = 0; m < 6; ++m) *(f16x8*)&Aa[base + (size_t)(m + 1) * DIN] = Bv[m];
}

// ---------------- Kernel 2: pack weights ----------------
__global__ __launch_bounds__(256) void build_W(const float* __restrict__ sb,
                                               const float* __restrict__ ssp,
                                               const float* __restrict__ coef,
                                               f16* __restrict__ Wa) {
  int idx = blockIdx.x * 256 + threadIdx.x;  // o*768 + i, exact grid
  float b = sb[idx];
  float sp = ssp[idx];
  int o = idx / DIN;
  int i = idx - o * DIN;
  size_t base = (size_t)o * KAUG + i;
  Wa[base] = (f16)b;
#pragma unroll
  for (int m = 0; m < 6; ++m)
    Wa[base + (size_t)(m + 1) * DIN] = (f16)(sp * coef[(size_t)idx * 6 + m]);
}

// ---------------- Kernel 3: GEMM C = A_aug * W_aug^T + bias ----------------
// 128x128 tile, 4 waves (2x2 of 64x64), BK=32, double-buffered LDS with the
// prefetch issued AFTER the barrier (single barrier per K-iter): the drain at
// the next barrier waits on a load that has had the whole compute phase to
// complete. XCD swizzle: the 6 N-blocks of one M-tile stay on one XCD.
__global__ __launch_bounds__(256) void kan_gemm(const f16* __restrict__ A,
                                                const f16* __restrict__ W,
                                                const float* __restrict__ bias,
                                                float* __restrict__ out) {
  __shared__ alignas(16) f16 As[2][BM * BK];  // 2 x 8 KB
  __shared__ alignas(16) f16 Bs[2][BN * BK];  // 2 x 8 KB

  const int bid = blockIdx.x;  // 384 = 8 XCD * 48 slots
  const int xcd = bid & 7;
  const int slot = bid >> 3;
  const int mb = ((slot & 7) << 3) + xcd;  // XCD x owns M-tiles m ≡ x (mod 8)
  const int nb = slot >> 3;                // 0..5
  const int m0 = mb * BM;
  const int n0 = nb * BN;

  const int tid = threadIdx.x;
  const int wave = tid >> 6;
  const int lane = tid & 63;
  const int wm = (wave >> 1) * 64;
  const int wn = (wave & 1) * 64;
  const int r = lane & 15;
  const int q = lane >> 4;

  f32x4 acc[4][4] = {};

  // staging chunk for instr s: c = s*256 + wave*64 + lane; row = c>>2, kblk = c&3
  const int c0 = wave * 64 + lane;
  const int rowA0 = c0 >> 2, kb0 = c0 & 3;
  const int c1 = c0 + 256;
  const int rowA1 = c1 >> 2, kb1 = c1 & 3;

  const f16* gA0 = A + (size_t)(m0 + rowA0) * KAUG + kb0 * 8;
  const f16* gA1 = A + (size_t)(m0 + rowA1) * KAUG + kb1 * 8;
  const f16* gB0 = W + (size_t)(n0 + rowA0) * KAUG + kb0 * 8;
  const f16* gB1 = W + (size_t)(n0 + rowA1) * KAUG + kb1 * 8;

  const int woff = wave * 512;  // f16 elements; 1 KB per wave

  auto stage = [&](int buf, int kt) {
    const int koff = kt * BK;
    __builtin_amdgcn_global_load_lds((gvoid*)(gA0 + koff), (lvoid*)(&As[buf][woff]), 16, 0, 0);
    __builtin_amdgcn_global_load_lds((gvoid*)(gA1 + koff), (lvoid*)(&As[buf][woff + 2048]), 16, 0, 0);
    __builtin_amdgcn_global_load_lds((gvoid*)(gB0 + koff), (lvoid*)(&Bs[buf][woff]), 16, 0, 0);
    __builtin_amdgcn_global_load_lds((gvoid*)(gB1 + koff), (lvoid*)(&Bs[buf][woff + 2048]), 16, 0, 0);
  };

  stage(0, 0);

  for (int kt = 0; kt < KT; ++kt) {
    const int buf = kt & 1;
    __syncthreads();  // drains the prefetch issued ~1 compute-phase ago; syncs LDS reuse
    if (kt + 1 < KT) stage(buf ^ 1, kt + 1);

    f16x8 af[4], bf[4];
#pragma unroll
    for (int mi = 0; mi < 4; ++mi)
      af[mi] = *(const f16x8*)&As[buf][(wm + mi * 16 + r) * BK + q * 8];
#pragma unroll
    for (int ni = 0; ni < 4; ++ni)
      bf[ni] = *(const f16x8*)&Bs[buf][(wn + ni * 16 + r) * BK + q * 8];
#pragma unroll
    for (int mi = 0; mi < 4; ++mi)
#pragma unroll
      for (int ni = 0; ni < 4; ++ni)
        acc[mi][ni] =
            __builtin_amdgcn_mfma_f32_16x16x32_f16(af[mi], bf[ni], acc[mi][ni], 0, 0, 0);
  }

  // epilogue: D mapping col = lane&15, row = q*4 + reg
#pragma unroll
  for (int ni = 0; ni < 4; ++ni) {
    const int gcol = n0 + wn + ni * 16 + r;
    const float bv = bias[gcol];
#pragma unroll
    for (int mi = 0; mi < 4; ++mi) {
#pragma unroll
      for (int rg = 0; rg < 4; ++rg) {
        const int grow = m0 + wm + mi * 16 + q * 4 + rg;
        out[(size_t)grow * DOUT + gcol] = acc[mi][ni][rg] + bv;
      }
    }
  }
}

extern "C" void kernel_launch(void* const* d_in, const int* in_sizes, int n_in,
                              void* d_out, int out_size, void* d_ws, size_t ws_size,
                              hipStream_t stream) {
  const float* x = (const float*)d_in[0];           // (4,2048,768)
  const float* coef = (const float*)d_in[1];        // (768,768,6)
  const float* scale_base = (const float*)d_in[2];  // (768,768)
  const float* scale_sp = (const float*)d_in[3];    // (768,768)
  const float* bias = (const float*)d_in[4];        // (768,)
  float* out = (float*)d_out;                       // (8192,768)

  f16* Aa = (f16*)d_ws;                                     // 8192*5376*2 = 88.1 MB
  f16* Wa = (f16*)((char*)d_ws + (size_t)NTOK * KAUG * 2);  // 768*5376*2  = 8.3 MB

  build_A<<<(NTOK * DIN / 8) / 256, 256, 0, stream>>>(x, Aa);
  build_W<<<(DOUT * DIN) / 256, 256, 0, stream>>>(scale_base, scale_sp, coef, Wa);
  kan_gemm<<<6 * 64, 256, 0, stream>>>(Aa, Wa, bias, out);
}

// Round 3
// 227.528 us; speedup vs baseline: 1.0512x; 1.0512x over previous
//
#include <hip/hip_runtime.h>
#include <hip/hip_bf16.h>

// KAN layer fused as one augmented GEMM:
//   out[n][o] = sum_i silu(x[n][i])*scale_base[o][i]
//            + sum_{i,m} basis_m(x[n][i])*scale_sp[o][i]*coef[o][i][m] + bias[o]
// A_aug (8192 x 5376) f16, W_aug (768 x 5376) f16, k = j*768 + i (j=0: silu, j=1..6: basis)
// GEMM is split-K x2: 768 blocks = exactly 3 blocks/CU; epilogue atomicAdd into
// zeroed d_out (bias folded into k-slice 0).

typedef _Float16 f16;
typedef __attribute__((ext_vector_type(8))) _Float16 f16x8;
typedef __attribute__((ext_vector_type(4))) float f32x4;

#define NTOK 8192
#define DIN 768
#define DOUT 768
#define KAUG 5376   // 7*768
#define BM 128
#define BN 128
#define BK 32
#define KSPLIT 2
#define KSEG (KAUG / KSPLIT)  // 2688
#define KT (KSEG / BK)        // 84

typedef __attribute__((address_space(1))) void gvoid;
typedef __attribute__((address_space(3))) void lvoid;

// ---------------- Kernel 1: x -> [silu | 6 basis] f16, 8 elems/thread ----------------
__global__ __launch_bounds__(256) void build_A(const float* __restrict__ x,
                                               f16* __restrict__ Aa) {
  const int t = blockIdx.x * 256 + threadIdx.x;  // [0, NTOK*96), exact grid
  const int n = t / 96;                          // 96 = DIN/8
  const int i8 = (t - n * 96) * 8;

  const float4* xp = (const float4*)(x + (size_t)n * DIN + i8);
  float4 va = xp[0], vb = xp[1];
  float xv[8] = {va.x, va.y, va.z, va.w, vb.x, vb.y, vb.z, vb.w};

  f16x8 sil;
  f16x8 Bv[6];
#pragma unroll
  for (int e = 0; e < 8; ++e) {
    const float v = xv[e];
    sil[e] = (f16)__fdividef(v, 1.0f + __expf(-v));

    const float s = (v + 1.0f) * 1.5f + 3.0f;
    const float fi = floorf(s);
    const int i0 = (int)fi;
    const float u = s - fi;
    const float um = 1.0f - u;
    const float u2 = u * u, u3 = u2 * u;
    const float w0 = um * um * um * (1.0f / 6.0f);
    const float w1 = (3.0f * u3 - 6.0f * u2 + 4.0f) * (1.0f / 6.0f);
    const float w2 = (-3.0f * u3 + 3.0f * u2 + 3.0f * u + 1.0f) * (1.0f / 6.0f);
    const float w3 = u3 * (1.0f / 6.0f);
#pragma unroll
    for (int m = 0; m < 6; ++m) {
      const int d = m - i0 + 3;  // which of the 4 weights (0..3), else zero
      float w = (d == 0) ? w0 : (d == 1) ? w1 : (d == 2) ? w2 : (d == 3) ? w3 : 0.0f;
      Bv[m][e] = (f16)w;
    }
  }

  const size_t base = (size_t)n * KAUG + i8;
  *(f16x8*)&Aa[base] = sil;
#pragma unroll
  for (int m = 0; m < 6; ++m) *(f16x8*)&Aa[base + (size_t)(m + 1) * DIN] = Bv[m];
}

// ---------------- Kernel 2: pack weights ----------------
__global__ __launch_bounds__(256) void build_W(const float* __restrict__ sb,
                                               const float* __restrict__ ssp,
                                               const float* __restrict__ coef,
                                               f16* __restrict__ Wa) {
  int idx = blockIdx.x * 256 + threadIdx.x;  // o*768 + i, exact grid
  float b = sb[idx];
  float sp = ssp[idx];
  int o = idx / DIN;
  int i = idx - o * DIN;
  size_t base = (size_t)o * KAUG + i;
  Wa[base] = (f16)b;
#pragma unroll
  for (int m = 0; m < 6; ++m)
    Wa[base + (size_t)(m + 1) * DIN] = (f16)(sp * coef[(size_t)idx * 6 + m]);
}

// ---------------- Kernel 3: GEMM C += A_aug * W_aug^T (+bias on slice 0) ----------------
// 128x128 tile, 4 waves (2x2 of 64x64), BK=32, split-K x2, double-buffered LDS,
// single barrier per K-iter (prefetch issued after the barrier). XCD swizzle:
// M-tiles striped across XCDs so A row-blocks stay XCD-local.
__global__ __launch_bounds__(256, 3) void kan_gemm(const f16* __restrict__ A,
                                                   const f16* __restrict__ W,
                                                   const float* __restrict__ bias,
                                                   float* __restrict__ out) {
  __shared__ alignas(16) f16 As[2][BM * BK];  // 2 x 8 KB
  __shared__ alignas(16) f16 Bs[2][BN * BK];  // 2 x 8 KB

  const int bid = blockIdx.x;        // 768 = 8 XCD * 96 slots
  const int xcd = bid & 7;
  const int slot = bid >> 3;         // 0..95
  const int mb = ((slot & 7) << 3) + xcd;  // 0..63, XCD x owns mb ≡ x (mod 8)
  const int rest = slot >> 3;        // 0..11
  const int nb = rest % 6;           // 0..5
  const int ks = rest / 6;           // 0..1
  const int m0 = mb * BM;
  const int n0 = nb * BN;
  const size_t kbase = (size_t)ks * KSEG;

  const int tid = threadIdx.x;
  const int wave = tid >> 6;
  const int lane = tid & 63;
  const int wm = (wave >> 1) * 64;
  const int wn = (wave & 1) * 64;
  const int r = lane & 15;
  const int q = lane >> 4;

  f32x4 acc[4][4] = {};

  // staging chunk for instr s: c = s*256 + wave*64 + lane; row = c>>2, kblk = c&3
  const int c0 = wave * 64 + lane;
  const int rowA0 = c0 >> 2, kb0 = c0 & 3;
  const int c1 = c0 + 256;
  const int rowA1 = c1 >> 2, kb1 = c1 & 3;

  const f16* gA0 = A + (size_t)(m0 + rowA0) * KAUG + kbase + kb0 * 8;
  const f16* gA1 = A + (size_t)(m0 + rowA1) * KAUG + kbase + kb1 * 8;
  const f16* gB0 = W + (size_t)(n0 + rowA0) * KAUG + kbase + kb0 * 8;
  const f16* gB1 = W + (size_t)(n0 + rowA1) * KAUG + kbase + kb1 * 8;

  const int woff = wave * 512;  // f16 elements; 1 KB per wave

  auto stage = [&](int buf, int kt) {
    const int koff = kt * BK;
    __builtin_amdgcn_global_load_lds((gvoid*)(gA0 + koff), (lvoid*)(&As[buf][woff]), 16, 0, 0);
    __builtin_amdgcn_global_load_lds((gvoid*)(gA1 + koff), (lvoid*)(&As[buf][woff + 2048]), 16, 0, 0);
    __builtin_amdgcn_global_load_lds((gvoid*)(gB0 + koff), (lvoid*)(&Bs[buf][woff]), 16, 0, 0);
    __builtin_amdgcn_global_load_lds((gvoid*)(gB1 + koff), (lvoid*)(&Bs[buf][woff + 2048]), 16, 0, 0);
  };

  stage(0, 0);

  for (int kt = 0; kt < KT; ++kt) {
    const int buf = kt & 1;
    __syncthreads();  // drains the prefetch issued ~1 compute-phase ago; syncs LDS reuse
    if (kt + 1 < KT) stage(buf ^ 1, kt + 1);

    f16x8 af[4], bf[4];
#pragma unroll
    for (int mi = 0; mi < 4; ++mi)
      af[mi] = *(const f16x8*)&As[buf][(wm + mi * 16 + r) * BK + q * 8];
#pragma unroll
    for (int ni = 0; ni < 4; ++ni)
      bf[ni] = *(const f16x8*)&Bs[buf][(wn + ni * 16 + r) * BK + q * 8];
#pragma unroll
    for (int mi = 0; mi < 4; ++mi)
#pragma unroll
      for (int ni = 0; ni < 4; ++ni)
        acc[mi][ni] =
            __builtin_amdgcn_mfma_f32_16x16x32_f16(af[mi], bf[ni], acc[mi][ni], 0, 0, 0);
  }

  // epilogue: D mapping col = lane&15, row = q*4 + reg; atomic into zeroed out
#pragma unroll
  for (int ni = 0; ni < 4; ++ni) {
    const int gcol = n0 + wn + ni * 16 + r;
    const float badd = (ks == 0) ? bias[gcol] : 0.0f;
#pragma unroll
    for (int mi = 0; mi < 4; ++mi) {
#pragma unroll
      for (int rg = 0; rg < 4; ++rg) {
        const int grow = m0 + wm + mi * 16 + q * 4 + rg;
        atomicAdd(&out[(size_t)grow * DOUT + gcol], acc[mi][ni][rg] + badd);
      }
    }
  }
}

extern "C" void kernel_launch(void* const* d_in, const int* in_sizes, int n_in,
                              void* d_out, int out_size, void* d_ws, size_t ws_size,
                              hipStream_t stream) {
  const float* x = (const float*)d_in[0];           // (4,2048,768)
  const float* coef = (const float*)d_in[1];        // (768,768,6)
  const float* scale_base = (const float*)d_in[2];  // (768,768)
  const float* scale_sp = (const float*)d_in[3];    // (768,768)
  const float* bias = (const float*)d_in[4];        // (768,)
  float* out = (float*)d_out;                       // (8192,768)

  f16* Aa = (f16*)d_ws;                                     // 8192*5376*2 = 88.1 MB
  f16* Wa = (f16*)((char*)d_ws + (size_t)NTOK * KAUG * 2);  // 768*5376*2  = 8.3 MB

  // zero the output for the atomic split-K epilogue (out is poisoned pre-launch)
  hipMemsetAsync(d_out, 0, (size_t)out_size * sizeof(float), stream);

  build_A<<<(NTOK * DIN / 8) / 256, 256, 0, stream>>>(x, Aa);
  build_W<<<(DOUT * DIN) / 256, 256, 0, stream>>>(scale_base, scale_sp, coef, Wa);
  kan_gemm<<<KSPLIT * 6 * 64, 256, 0, stream>>>(Aa, Wa, bias, out);
}